// Round 6
// baseline (173.723 us; speedup 1.0000x reference)
//
#include <hip/hip_runtime.h>
#include <math.h>

#define B_ 8
#define C_ 128
#define N_ 3136          // 56*56
#define MT2 128          // m per fused iteration (two 64-m tiles)
#define NIT 25           // ceil(N_/MT2); last iteration has 64 valid m
#define SLICES 98        // prep: N_/32
#define QTBIG 128        // q rows per block
#define QTILES 25        // ceil(N_/QTBIG)
#define CS_STRIDE 100    // csump padded slice stride

typedef short bf16x8 __attribute__((ext_vector_type(8)));
typedef float f32x4 __attribute__((ext_vector_type(4)));

__device__ __forceinline__ unsigned short f2bf(float f) {
    union { float f; unsigned u; } x; x.f = f;
    return (unsigned short)((x.u + 0x8000u) >> 16);   // round-half-up to bf16
}

__device__ __forceinline__ void gl_lds16(const void* g, void* l) {
    __builtin_amdgcn_global_load_lds(
        (const __attribute__((address_space(1))) unsigned int*)g,
        (__attribute__((address_space(3))) unsigned int*)l, 16, 0, 0);
}

// ---------------------------------------------------------------------------
// colsum (fallback path only)
// ---------------------------------------------------------------------------
__global__ __launch_bounds__(256) void colsum_kernel(const float* __restrict__ s,
                                                     float* __restrict__ csum) {
    int blk = blockIdx.x;  // = b*C_ + c
    const float* p = s + (size_t)blk * N_;
    float acc = 0.f;
    for (int i = threadIdx.x; i < N_; i += 256) acc += p[i];
#pragma unroll
    for (int off = 32; off > 0; off >>= 1) acc += __shfl_down(acc, off, 64);
    __shared__ float part[4];
    if ((threadIdx.x & 63) == 0) part[threadIdx.x >> 6] = acc;
    __syncthreads();
    if (threadIdx.x == 0) csum[blk] = part[0] + part[1] + part[2] + part[3];
}

// ---------------------------------------------------------------------------
// Prepass, per (b, 32-m slice) -- 784 blocks (~3/CU) for latency hiding:
//   sfT[b][m][c] bf16, chunks XOR-swizzled by sigma(m)=(m&15)^((m>>1)&4)
//   qfT[b][tile64 t][p(8)][c][8] bf16 V-panels (PV fragment layout)
//   csump[b][c][slice] = partial column sums of s (deterministic)
// ---------------------------------------------------------------------------
__global__ __launch_bounds__(256) void prep_kernel(const float* __restrict__ q,
                                                   const float* __restrict__ s,
                                                   unsigned short* __restrict__ sfT,
                                                   unsigned short* __restrict__ qfT,
                                                   float* __restrict__ csump) {
    __shared__ unsigned short T[4608];   // 9.2KB, reused by both phases
    const int tid = threadIdx.x, bid = blockIdx.x;
    const int b = bid & 7, m0 = (bid >> 3) * 32;
    const int slice = bid >> 3;          // 0..97
    const float* sb = s + (size_t)b * C_ * N_;
    const float* qb = q + (size_t)b * C_ * N_;

    // ---- phase A: transpose s [c][32m] -> TA[32][c] + colsum partials ----
    unsigned short (*TA)[132] = (unsigned short (*)[132])T;   // [32][132]
#pragma unroll
    for (int st = 0; st < 4; ++st) {
        int idx = st * 256 + tid;            // [0,1024)
        int c = idx >> 3, m4 = (idx & 7) * 4;
        float4 v = *(const float4*)&sb[(size_t)c * N_ + m0 + m4];
        TA[m4 + 0][c] = f2bf(v.x);
        TA[m4 + 1][c] = f2bf(v.y);
        TA[m4 + 2][c] = f2bf(v.z);
        TA[m4 + 3][c] = f2bf(v.w);
        float ps = (v.x + v.y) + (v.z + v.w);
        ps += __shfl_xor(ps, 1, 8);
        ps += __shfl_xor(ps, 2, 8);
        ps += __shfl_xor(ps, 4, 8);
        if ((tid & 7) == 0) csump[((size_t)b * C_ + c) * CS_STRIDE + slice] = ps;
    }
    __syncthreads();
    {
        unsigned short* dst = sfT + (size_t)b * N_ * C_;
#pragma unroll
        for (int st = 0; st < 2; ++st) {
            int g = st * 256 + tid;          // [0,512)
            int mr = g >> 4, p = g & 15;
            int sw = (mr & 15) ^ ((mr >> 1) & 4);   // sigma(m mod 16)
            int lch = p ^ sw;                       // baked XOR swizzle
            const unsigned short* src = &TA[mr][lch * 8];
            ushort4 a = *(const ushort4*)src;
            ushort4 bq = *(const ushort4*)(src + 4);
            uint4 w;
            w.x = a.x | ((unsigned)a.y << 16);   w.y = a.z | ((unsigned)a.w << 16);
            w.z = bq.x | ((unsigned)bq.y << 16); w.w = bq.z | ((unsigned)bq.w << 16);
            *(uint4*)&dst[(size_t)(m0 + mr) * C_ + p * 8] = w;
        }
    }
    __syncthreads();   // T reuse

    // ---- phase B: qfT V-panels [t][p][c][8] ----
    unsigned short (*TB)[34] = (unsigned short (*)[34])T;     // [128][34]
#pragma unroll
    for (int st = 0; st < 4; ++st) {
        int idx = st * 256 + tid;            // [0,1024)
        int r = idx >> 5, c4 = (idx & 31) * 4;
        float4 v = *(const float4*)&qb[(size_t)(m0 + r) * C_ + c4];
        TB[c4 + 0][r] = f2bf(v.x);
        TB[c4 + 1][r] = f2bf(v.y);
        TB[c4 + 2][r] = f2bf(v.z);
        TB[c4 + 3][r] = f2bf(v.w);
    }
    __syncthreads();
    {
        unsigned short* dstb = qfT + (size_t)b * N_ * C_;
        const int tile = m0 >> 6, pbase = (m0 & 32) >> 3;     // 0 or 4
#pragma unroll
        for (int st = 0; st < 2; ++st) {
            int g = st * 256 + tid;          // [0,512)
            int pl = g >> 7, c = g & 127;
            const unsigned short* src = &TB[c][pl * 8];
            ushort2 a0 = *(const ushort2*)(src);
            ushort2 a1 = *(const ushort2*)(src + 2);
            ushort2 a2 = *(const ushort2*)(src + 4);
            ushort2 a3 = *(const ushort2*)(src + 6);
            uint4 w;
            w.x = a0.x | ((unsigned)a0.y << 16); w.y = a1.x | ((unsigned)a1.y << 16);
            w.z = a2.x | ((unsigned)a2.y << 16); w.w = a3.x | ((unsigned)a3.y << 16);
            *(uint4*)&dstb[((size_t)tile * 8 + pbase + pl) * (C_ * 8) + c * 8] = w;
        }
    }
}

// ---------------------------------------------------------------------------
// Single-pass fused kernel, tile-pair structure. grid = 25 q-tiles x 8
// batches = 200 blocks of 512 threads. __launch_bounds__(512,1): 1 block/CU
// (LDS 134KB only fits one) -> VGPR cap 256/lane. Round-5's (512,2) capped
// VGPRs at 128 and spilled the 192-reg persistent state to scratch
// (WRITE_SIZE 25->36MB, dur 84->126us). 8 waves = 2 q-subgroups (qs: 64
// rows, rt=4) x 2 tile-slots (tp) x 2 m-groups (mg). Each iteration stages
// 128 m (two 64-m tiles, 64KB) double-buffered; af/vf LDS bytes per MFMA
// halved vs the 64-m round-3 loop, barriers per m halved.
// ---------------------------------------------------------------------------
__global__ __launch_bounds__(512, 1) void fused_full_kernel(
    const float* __restrict__ q, const float* __restrict__ s,
    const float* __restrict__ csump,
    const unsigned short* __restrict__ sfT,
    const unsigned short* __restrict__ qfT,
    float* __restrict__ out0, float* __restrict__ out1) {

    __shared__ __align__(16) unsigned char SM[131072];  // 2 x (K32KB + V32KB) | Of
    __shared__ float dred[4][QTBIG];
    __shared__ float mskd[QTBIG];
    __shared__ float cs[C_];

    float (*Of)[132] = (float (*)[132])SM;              // [128][132] epilogue

    const int tid = threadIdx.x;
    const int lane = tid & 63;
    const int wave = tid >> 6;             // 0..7
    const int l15 = lane & 15;
    const int quad = lane >> 4;
    const int qs = wave >> 2;              // q-subgroup: rows qs*64..qs*64+63
    const int tp = (wave >> 1) & 1;        // tile-slot within 128-m pair
    const int mg = wave & 1;               // m-group: 32-m half of 64-m tile
    const int bid = blockIdx.x;
    const int b = bid & 7;                 // XCD-pinned batch
    const int qt = bid >> 3;               // 0..24
    const int n0 = qt * QTBIG;

    const float* qb = q + (size_t)b * C_ * N_;
    const unsigned short* sfTb = sfT + (size_t)b * N_ * C_;
    const unsigned short* qfTb = qfT + (size_t)b * N_ * C_;

    // sigma(l15) base: permuted-m row so exp'd C-values form the PV A-frag
    const int sig_base = ((l15 >> 2) << 3) + (l15 & 3);

    // ---- prologue: async-stage iteration 0 into buffer 0 ----
#pragma unroll
    for (int st = 0; st < 4; ++st) {
        int i = st * 512 + tid;
        gl_lds16(sfTb + (size_t)(i >> 4) * C_ + (i & 15) * 8,
                 SM + (st * 512 + wave * 64) * 16);
        gl_lds16(qfTb + (size_t)i * 8,
                 SM + 32768 + (st * 512 + wave * 64) * 16);
    }

    // ---- csum gather: contiguous per-channel partial sums ----
    if (tid < C_) {
        float a = 0.f;
        const float* cp = csump + ((size_t)b * C_ + tid) * CS_STRIDE;
#pragma unroll 7
        for (int sl = 0; sl < SLICES; ++sl) a += cp[sl];
        cs[tid] = a;
    }
    __syncthreads();   // cs visible

    // ---- Q fragments (registers for all tiles) + fp32 mask-dot ----
    bf16x8 qa[4][4];
    float dotp[4];
#pragma unroll
    for (int rt = 0; rt < 4; ++rt) {
        int grow = n0 + qs * 64 + rt * 16 + l15;
        if (grow > N_ - 1) grow = N_ - 1;   // pad rows duplicate last row
        float dp = 0.f;
#pragma unroll
        for (int ks = 0; ks < 4; ++ks) {
            int c0 = ks * 32 + quad * 8;
            float4 f0 = *(const float4*)&qb[(size_t)grow * C_ + c0];
            float4 f1 = *(const float4*)&qb[(size_t)grow * C_ + c0 + 4];
            dp += f0.x * cs[c0 + 0] + f0.y * cs[c0 + 1] +
                  f0.z * cs[c0 + 2] + f0.w * cs[c0 + 3] +
                  f1.x * cs[c0 + 4] + f1.y * cs[c0 + 5] +
                  f1.z * cs[c0 + 6] + f1.w * cs[c0 + 7];
            union { unsigned short u[8]; bf16x8 v; } t;
            t.u[0] = f2bf(f0.x); t.u[1] = f2bf(f0.y);
            t.u[2] = f2bf(f0.z); t.u[3] = f2bf(f0.w);
            t.u[4] = f2bf(f1.x); t.u[5] = f2bf(f1.y);
            t.u[6] = f2bf(f1.z); t.u[7] = f2bf(f1.w);
            qa[rt][ks] = t.v;
        }
        dotp[rt] = dp;
    }
#pragma unroll
    for (int rt = 0; rt < 4; ++rt) {
        float d = dotp[rt];
        d += __shfl_xor(d, 16, 64);
        d += __shfl_xor(d, 32, 64);
        if (tp == 0 && mg == 0 && quad == 0) mskd[qs * 64 + rt * 16 + l15] = d;
    }

    f32x4 O[4][8];
#pragma unroll
    for (int rt = 0; rt < 4; ++rt)
#pragma unroll
        for (int nt = 0; nt < 8; ++nt) O[rt][nt] = (f32x4){0.f, 0.f, 0.f, 0.f};
    float dsum[4] = {0.f, 0.f, 0.f, 0.f};

    for (int it = 0; it < NIT; ++it) {
        const int cur = it & 1;
        const int vm = (N_ - it * MT2 >= MT2) ? MT2 : (N_ - it * MT2);
        __syncthreads();   // staging for this iteration complete

        if (it + 1 < NIT) {               // async-prefetch next 128-m pair
            const int nxt = cur ^ 1;
            const int m1 = (it + 1) * MT2;
            const int vmn = (N_ - m1 >= MT2) ? MT2 : (N_ - m1);
            unsigned char* Kb = SM + nxt * 65536;
            unsigned char* Vb = Kb + 32768;
#pragma unroll
            for (int st = 0; st < 4; ++st) {
                if (st * 32 < vmn) {
                    int i = st * 512 + tid;
                    gl_lds16(sfTb + ((size_t)m1 + (i >> 4)) * C_ + (i & 15) * 8,
                             Kb + (st * 512 + wave * 64) * 16);
                }
            }
#pragma unroll
            for (int st = 0; st < 4; ++st) {
                if (st * 32 < vmn) {
                    int i = st * 512 + tid;
                    gl_lds16(qfTb + (size_t)(m1 >> 6) * 8192 + (size_t)i * 8,
                             Vb + (st * 512 + wave * 64) * 16);
                }
            }
        }

        if (tp * 64 < vm) {               // tail: tp=1 waves idle at it=24
            const unsigned short* KbS = (const unsigned short*)(SM + cur * 65536);
            const unsigned short* VbS = (const unsigned short*)(SM + cur * 65536 + 32768) + tp * 8192;

            // ---- scoresT: rows = permuted m (wave's 32-m sub), cols = q ----
            f32x4 acc[2][4];
            __builtin_amdgcn_s_setprio(1);
#pragma unroll
            for (int ct = 0; ct < 2; ++ct) {
                const int mrow = sig_base + (ct << 2);           // 0..31 perm
                const int sw = (mrow & 15) ^ ((mrow >> 1) & 4);  // sigma
                const int row = tp * 64 + mg * 32 + mrow;
#pragma unroll
                for (int rt = 0; rt < 4; ++rt) acc[ct][rt] = (f32x4){0.f, 0.f, 0.f, 0.f};
#pragma unroll
                for (int ks = 0; ks < 4; ++ks) {
                    int ch = (ks * 4 + quad) ^ sw;               // un-swizzle
                    bf16x8 af = *(const bf16x8*)&KbS[row * C_ + ch * 8];
                    acc[ct][0] = __builtin_amdgcn_mfma_f32_16x16x32_bf16(af, qa[0][ks], acc[ct][0], 0, 0, 0);
                    acc[ct][1] = __builtin_amdgcn_mfma_f32_16x16x32_bf16(af, qa[1][ks], acc[ct][1], 0, 0, 0);
                    acc[ct][2] = __builtin_amdgcn_mfma_f32_16x16x32_bf16(af, qa[2][ks], acc[ct][2], 0, 0, 0);
                    acc[ct][3] = __builtin_amdgcn_mfma_f32_16x16x32_bf16(af, qa[3][ks], acc[ct][3], 0, 0, 0);
                }
            }
            __builtin_amdgcn_s_setprio(0);

            // ---- exp + in-lane pack into PV A-fragments ----
            bf16x8 pa[4];
#pragma unroll
            for (int rt = 0; rt < 4; ++rt) {
                float e0 = __expf(acc[0][rt][0]);
                float e1 = __expf(acc[0][rt][1]);
                float e2 = __expf(acc[0][rt][2]);
                float e3 = __expf(acc[0][rt][3]);
                float e4 = __expf(acc[1][rt][0]);
                float e5 = __expf(acc[1][rt][1]);
                float e6 = __expf(acc[1][rt][2]);
                float e7 = __expf(acc[1][rt][3]);
                dsum[rt] += ((e0 + e1) + (e2 + e3)) + ((e4 + e5) + (e6 + e7));
                union { unsigned short u[8]; bf16x8 v; } pk;
                pk.u[0] = f2bf(e0); pk.u[1] = f2bf(e1);
                pk.u[2] = f2bf(e2); pk.u[3] = f2bf(e3);
                pk.u[4] = f2bf(e4); pk.u[5] = f2bf(e5);
                pk.u[6] = f2bf(e6); pk.u[7] = f2bf(e7);
                pa[rt] = pk.v;
            }

            // ---- PV: O[rt][nt] += P x V (conflict-free V panels) ----
            __builtin_amdgcn_s_setprio(1);
#pragma unroll
            for (int nt = 0; nt < 8; ++nt) {
                bf16x8 vf = *(const bf16x8*)&VbS[((mg * 4 + quad) * C_ + nt * 16 + l15) * 8];
                O[0][nt] = __builtin_amdgcn_mfma_f32_16x16x32_bf16(pa[0], vf, O[0][nt], 0, 0, 0);
                O[1][nt] = __builtin_amdgcn_mfma_f32_16x16x32_bf16(pa[1], vf, O[1][nt], 0, 0, 0);
                O[2][nt] = __builtin_amdgcn_mfma_f32_16x16x32_bf16(pa[2], vf, O[2][nt], 0, 0, 0);
                O[3][nt] = __builtin_amdgcn_mfma_f32_16x16x32_bf16(pa[3], vf, O[3][nt], 0, 0, 0);
            }
            __builtin_amdgcn_s_setprio(0);
        }
    }

    // ---- denominator: reduce over quads, publish per (tp,mg) ----
    const int part = tp * 2 + mg;
#pragma unroll
    for (int rt = 0; rt < 4; ++rt) {
        float d = dsum[rt];
        d += __shfl_xor(d, 16, 64);
        d += __shfl_xor(d, 32, 64);
        if (quad == 0) dred[part][qs * 64 + rt * 16 + l15] = d;
    }
    __syncthreads();   // all PV reads of staging done; SM becomes Of

    // ---- O reduction across 4 (tp,mg) partials via LDS ----
    if (part == 3) {
#pragma unroll
        for (int rt = 0; rt < 4; ++rt)
#pragma unroll
            for (int nt = 0; nt < 8; ++nt)
#pragma unroll
                for (int r = 0; r < 4; ++r)
                    Of[qs * 64 + rt * 16 + quad * 4 + r][nt * 16 + l15] = O[rt][nt][r];
    }
    __syncthreads();
    if (part == 2) {
#pragma unroll
        for (int rt = 0; rt < 4; ++rt)
#pragma unroll
            for (int nt = 0; nt < 8; ++nt)
#pragma unroll
                for (int r = 0; r < 4; ++r)
                    Of[qs * 64 + rt * 16 + quad * 4 + r][nt * 16 + l15] += O[rt][nt][r];
    }
    __syncthreads();
    if (part == 1) {
#pragma unroll
        for (int rt = 0; rt < 4; ++rt)
#pragma unroll
            for (int nt = 0; nt < 8; ++nt)
#pragma unroll
                for (int r = 0; r < 4; ++r)
                    Of[qs * 64 + rt * 16 + quad * 4 + r][nt * 16 + l15] += O[rt][nt][r];
    }
    __syncthreads();
    if (part == 0) {
#pragma unroll
        for (int rt = 0; rt < 4; ++rt)
#pragma unroll
            for (int nt = 0; nt < 8; ++nt)
#pragma unroll
                for (int r = 0; r < 4; ++r)
                    Of[qs * 64 + rt * 16 + quad * 4 + r][nt * 16 + l15] += O[rt][nt][r];
    }
    __syncthreads();

    // ---- final coalesced pass: normalize, mask, residuals, both outputs ----
    const size_t vbase = (size_t)b * N_ * C_ + (size_t)n0 * C_;
#pragma unroll
    for (int it2 = 0; it2 < 8; ++it2) {
        int row = it2 * 16 + (tid >> 5);
        int grow = n0 + row;
        if (grow >= N_) continue;
        int c = (tid & 31) * 4;
        float dt = (dred[0][row] + dred[1][row]) + (dred[2][row] + dred[3][row]);
        float mk = 1.0f / (1.0f + __expf(-mskd[row]));
        float scl = mk / dt;
        float om = 1.0f + mk;
        float4 o4 = *(const float4*)&Of[row][c];
        float4 q4 = *(const float4*)&q[vbase + (size_t)row * C_ + c];
        float4 s4 = *(const float4*)&s[vbase + (size_t)row * C_ + c];
        float4 r0v, r1v;
        r0v.x = q4.x + o4.x * scl;
        r0v.y = q4.y + o4.y * scl;
        r0v.z = q4.z + o4.z * scl;
        r0v.w = q4.w + o4.w * scl;
        r1v.x = s4.x * om; r1v.y = s4.y * om;
        r1v.z = s4.z * om; r1v.w = s4.w * om;
        *(float4*)&out0[vbase + (size_t)row * C_ + c] = r0v;
        *(float4*)&out1[vbase + (size_t)row * C_ + c] = r1v;
    }
}

// ---------------------------------------------------------------------------
// fp32 fallback kernel (only if ws_size too small for sfT/qfT).
// ---------------------------------------------------------------------------
__global__ __launch_bounds__(256, 2) void fused_kernel(const float* __restrict__ q,
                                                       const float* __restrict__ s,
                                                       const float* __restrict__ csum,
                                                       float* __restrict__ out0,
                                                       float* __restrict__ out1) {
    __shared__ float QtT[C_][68];
    __shared__ float Kt[C_ * 32];
    __shared__ float Vt[32 * C_];
    __shared__ float PT[32][68];
    __shared__ float mask_l[64];
    __shared__ float csum_l[C_];

    const int t = threadIdx.x;
    const int l = t & 63, w = t >> 6, tx = t & 15, ty = t >> 4;
    const int bid = blockIdx.x, b = bid & 7, n0 = (bid >> 3) * 64;
    const float* qb = q + (size_t)b * C_ * N_;
    const float* sb = s + (size_t)b * C_ * N_;

#pragma unroll
    for (int jj = 0; jj < 2; ++jj) {
        int c = l + 64 * jj;
#pragma unroll
        for (int i = 0; i < 16; ++i) QtT[c][w + 4 * i] = qb[(size_t)(n0 + w + 4 * i) * C_ + c];
    }
    if (t < C_) csum_l[t] = csum[b * C_ + t];
    __syncthreads();
    if (t < 64) {
        float d = 0.f;
        for (int c = 0; c < C_; ++c) d += QtT[c][t] * csum_l[c];
        mask_l[t] = 1.0f / (1.0f + __expf(-d));
    }
    float4 Oa[4], Ob[4];
#pragma unroll
    for (int i = 0; i < 4; ++i) { Oa[i] = make_float4(0,0,0,0); Ob[i] = make_float4(0,0,0,0); }
    float m_r[4], l_r[4];
#pragma unroll
    for (int i = 0; i < 4; ++i) { m_r[i] = -3.0e38f; l_r[i] = 0.f; }

    for (int mt = 0; mt < N_ / 32; ++mt) {
        const int m0 = mt * 32;
        __syncthreads();
#pragma unroll
        for (int i = 0; i < 4; ++i) {
            int s4 = (w * 4 + i) * 64 + l;
            int c = s4 >> 3, mq = (s4 & 7) * 4;
            *(float4*)&Kt[c * 32 + mq] = *(const float4*)&sb[(size_t)c * N_ + m0 + mq];
            *(float4*)&Vt[s4 * 4] = *(const float4*)&qb[(size_t)m0 * C_ + s4 * 4];
        }
        __syncthreads();
        float a[4][2];
#pragma unroll
        for (int i = 0; i < 4; ++i) a[i][0] = a[i][1] = 0.f;
#pragma unroll 4
        for (int k = 0; k < C_; ++k) {
            const float4 qv = *(const float4*)&QtT[k][4 * ty];
            const float2 kv = *(const float2*)&Kt[k * 32 + 2 * tx];
            a[0][0] = fmaf(qv.x, kv.x, a[0][0]); a[0][1] = fmaf(qv.x, kv.y, a[0][1]);
            a[1][0] = fmaf(qv.y, kv.x, a[1][0]); a[1][1] = fmaf(qv.y, kv.y, a[1][1]);
            a[2][0] = fmaf(qv.z, kv.x, a[2][0]); a[2][1] = fmaf(qv.z, kv.y, a[2][1]);
            a[3][0] = fmaf(qv.w, kv.x, a[3][0]); a[3][1] = fmaf(qv.w, kv.y, a[3][1]);
        }
#pragma unroll
        for (int i = 0; i < 4; ++i) {
            float tm = fmaxf(a[i][0], a[i][1]);
            tm = fmaxf(tm, __shfl_xor(tm, 1, 64)); tm = fmaxf(tm, __shfl_xor(tm, 2, 64));
            tm = fmaxf(tm, __shfl_xor(tm, 4, 64)); tm = fmaxf(tm, __shfl_xor(tm, 8, 64));
            float nm = fmaxf(m_r[i], tm);
            float al = __expf(m_r[i] - nm);
            m_r[i] = nm;
            float p0 = __expf(a[i][0] - nm), p1 = __expf(a[i][1] - nm);
            float ts = p0 + p1;
            ts += __shfl_xor(ts, 1, 64); ts += __shfl_xor(ts, 2, 64);
            ts += __shfl_xor(ts, 4, 64); ts += __shfl_xor(ts, 8, 64);
            l_r[i] = l_r[i] * al + ts;
            PT[2 * tx + 0][4 * ty + i] = p0;
            PT[2 * tx + 1][4 * ty + i] = p1;
            Oa[i].x *= al; Oa[i].y *= al; Oa[i].z *= al; Oa[i].w *= al;
            Ob[i].x *= al; Ob[i].y *= al; Ob[i].z *= al; Ob[i].w *= al;
        }
        __syncthreads();
#pragma unroll 2
        for (int j = 0; j < 32; ++j) {
            const float4 pv = *(const float4*)&PT[j][4 * ty];
            const float4 v0 = *(const float4*)&Vt[j * C_ + 4 * tx];
            const float4 v1 = *(const float4*)&Vt[j * C_ + 4 * tx + 64];
            Oa[0].x = fmaf(pv.x, v0.x, Oa[0].x); Oa[0].y = fmaf(pv.x, v0.y, Oa[0].y);
            Oa[0].z = fmaf(pv.x, v0.z, Oa[0].z); Oa[0].w = fmaf(pv.x, v0.w, Oa[0].w);
            Ob[0].x = fmaf(pv.x, v1.x, Ob[0].x); Ob[0].y = fmaf(pv.x, v1.y, Ob[0].y);
            Ob[0].z = fmaf(pv.x, v1.z, Ob[0].z); Ob[0].w = fmaf(pv.x, v1.w, Ob[0].w);
            Oa[1].x = fmaf(pv.y, v0.x, Oa[1].x); Oa[1].y = fmaf(pv.y, v0.y, Oa[1].y);
            Oa[1].z = fmaf(pv.y, v0.z, Oa[1].z); Oa[1].w = fmaf(pv.y, v0.w, Oa[1].w);
            Ob[1].x = fmaf(pv.y, v1.x, Ob[1].x); Ob[1].y = fmaf(pv.y, v1.y, Ob[1].y);
            Ob[1].z = fmaf(pv.y, v1.z, Ob[1].z); Ob[1].w = fmaf(pv.y, v1.w, Ob[1].w);
            Oa[2].x = fmaf(pv.z, v0.x, Oa[2].x); Oa[2].y = fmaf(pv.z, v0.y, Oa[2].y);
            Oa[2].z = fmaf(pv.z, v0.z, Oa[2].z); Oa[2].w = fmaf(pv.z, v0.w, Oa[2].w);
            Ob[2].x = fmaf(pv.z, v1.x, Ob[2].x); Ob[2].y = fmaf(pv.z, v1.y, Ob[2].y);
            Ob[2].z = fmaf(pv.z, v1.z, Ob[2].z); Ob[2].w = fmaf(pv.z, v1.w, Ob[2].w);
            Oa[3].x = fmaf(pv.w, v0.x, Oa[3].x); Oa[3].y = fmaf(pv.w, v0.y, Oa[3].y);
            Oa[3].z = fmaf(pv.w, v0.z, Oa[3].z); Oa[3].w = fmaf(pv.w, v0.w, Oa[3].w);
            Ob[3].x = fmaf(pv.w, v1.x, Ob[3].x); Ob[3].y = fmaf(pv.w, v1.y, Ob[3].y);
            Ob[3].z = fmaf(pv.w, v1.z, Ob[3].z); Ob[3].w = fmaf(pv.w, v1.w, Ob[3].w);
        }
    }
#pragma unroll
    for (int i = 0; i < 4; ++i) {
        const int r = 4 * ty + i;
        const float mk = mask_l[r];
        const float scl = mk / l_r[i];
        const float om = 1.0f + mk;
        const size_t row = (size_t)b * C_ * N_ + (size_t)(n0 + r) * C_;
#pragma unroll
        for (int h = 0; h < 2; ++h) {
            const int c = 4 * tx + 64 * h;
            const float4 ov = h ? Ob[i] : Oa[i];
            float4 qv = *(const float4*)&qb[(size_t)(n0 + r) * C_ + c];
            float4 sv = *(const float4*)&sb[(size_t)(n0 + r) * C_ + c];
            float4 o0, o1;
            o0.x = qv.x + ov.x * scl; o0.y = qv.y + ov.y * scl;
            o0.z = qv.z + ov.z * scl; o0.w = qv.w + ov.w * scl;
            o1.x = sv.x * om; o1.y = sv.y * om; o1.z = sv.z * om; o1.w = sv.w * om;
            *(float4*)&out0[row + c] = o0;
            *(float4*)&out1[row + c] = o1;
        }
    }
}

extern "C" void kernel_launch(void* const* d_in, const int* in_sizes, int n_in,
                              void* d_out, int out_size, void* d_ws, size_t ws_size,
                              hipStream_t stream) {
    const float* q = (const float*)d_in[0];
    const float* s = (const float*)d_in[1];
    float* out0 = (float*)d_out;
    float* out1 = out0 + (size_t)B_ * C_ * N_;

    const size_t elems = (size_t)B_ * N_ * C_;              // 3.21M
    const size_t csump_sz = (size_t)B_ * C_ * CS_STRIDE;    // 102400 floats
    const size_t need = csump_sz * sizeof(float)
                      + 2 * elems * sizeof(unsigned short); // sfT + qfT

    if (ws_size >= need) {
        float* csump = (float*)d_ws;
        unsigned short* sfT = (unsigned short*)(csump + csump_sz);
        unsigned short* qfT = sfT + elems;
        prep_kernel<<<B_ * SLICES, 256, 0, stream>>>(q, s, sfT, qfT, csump);
        fused_full_kernel<<<QTILES * B_, 512, 0, stream>>>(q, s, csump, sfT, qfT, out0, out1);
    } else {
        float* csum = (float*)d_ws;                   // 4KB
        colsum_kernel<<<B_ * C_, 256, 0, stream>>>(s, csum);
        fused_kernel<<<B_ * (N_ / 64), 256, 0, stream>>>(q, s, csum, out0, out1);
    }
}

// Round 7
// 152.551 us; speedup vs baseline: 1.1388x; 1.1388x over previous
//
#include <hip/hip_runtime.h>
#include <math.h>

#define B_ 8
#define C_ 128
#define N_ 3136          // 56*56
#define MT 64            // m per tile
#define TILES 49         // N_/MT
#define SLICES 98        // prep: N_/32
#define QTBIG 128        // q rows per block
#define QTILES 25        // ceil(N_/QTBIG)
#define CS_STRIDE 100    // csump padded slice stride

typedef short bf16x8 __attribute__((ext_vector_type(8)));
typedef float f32x4 __attribute__((ext_vector_type(4)));

__device__ __forceinline__ unsigned short f2bf(float f) {
    union { float f; unsigned u; } x; x.f = f;
    return (unsigned short)((x.u + 0x8000u) >> 16);   // round-half-up to bf16
}

__device__ __forceinline__ unsigned cvtpk(float lo, float hi) {
    unsigned r;
    asm("v_cvt_pk_bf16_f32 %0, %1, %2" : "=v"(r) : "v"(lo), "v"(hi));
    return r;
}

__device__ __forceinline__ void gl_lds16(const void* g, void* l) {
    __builtin_amdgcn_global_load_lds(
        (const __attribute__((address_space(1))) unsigned int*)g,
        (__attribute__((address_space(3))) unsigned int*)l, 16, 0, 0);
}

// ---------------------------------------------------------------------------
// colsum (fallback path only)
// ---------------------------------------------------------------------------
__global__ __launch_bounds__(256) void colsum_kernel(const float* __restrict__ s,
                                                     float* __restrict__ csum) {
    int blk = blockIdx.x;  // = b*C_ + c
    const float* p = s + (size_t)blk * N_;
    float acc = 0.f;
    for (int i = threadIdx.x; i < N_; i += 256) acc += p[i];
#pragma unroll
    for (int off = 32; off > 0; off >>= 1) acc += __shfl_down(acc, off, 64);
    __shared__ float part[4];
    if ((threadIdx.x & 63) == 0) part[threadIdx.x >> 6] = acc;
    __syncthreads();
    if (threadIdx.x == 0) csum[blk] = part[0] + part[1] + part[2] + part[3];
}

// ---------------------------------------------------------------------------
// Prepass, per (b, 32-m slice) -- 784 blocks (~3/CU) for latency hiding:
//   sfT[b][m][c] bf16, chunks XOR-swizzled by sigma(m)=(m&15)^((m>>1)&4)
//   qfT[b][tile64 t][p(8)][c][8] bf16 V-panels (PV fragment layout)
//   csump[b][c][slice] = partial column sums of s (deterministic)
// ---------------------------------------------------------------------------
__global__ __launch_bounds__(256) void prep_kernel(const float* __restrict__ q,
                                                   const float* __restrict__ s,
                                                   unsigned short* __restrict__ sfT,
                                                   unsigned short* __restrict__ qfT,
                                                   float* __restrict__ csump) {
    __shared__ unsigned short T[4608];   // 9.2KB, reused by both phases
    const int tid = threadIdx.x, bid = blockIdx.x;
    const int b = bid & 7, m0 = (bid >> 3) * 32;
    const int slice = bid >> 3;          // 0..97
    const float* sb = s + (size_t)b * C_ * N_;
    const float* qb = q + (size_t)b * C_ * N_;

    // ---- phase A: transpose s [c][32m] -> TA[32][c] + colsum partials ----
    unsigned short (*TA)[132] = (unsigned short (*)[132])T;   // [32][132]
#pragma unroll
    for (int st = 0; st < 4; ++st) {
        int idx = st * 256 + tid;            // [0,1024)
        int c = idx >> 3, m4 = (idx & 7) * 4;
        float4 v = *(const float4*)&sb[(size_t)c * N_ + m0 + m4];
        TA[m4 + 0][c] = f2bf(v.x);
        TA[m4 + 1][c] = f2bf(v.y);
        TA[m4 + 2][c] = f2bf(v.z);
        TA[m4 + 3][c] = f2bf(v.w);
        float ps = (v.x + v.y) + (v.z + v.w);
        ps += __shfl_xor(ps, 1, 8);
        ps += __shfl_xor(ps, 2, 8);
        ps += __shfl_xor(ps, 4, 8);
        if ((tid & 7) == 0) csump[((size_t)b * C_ + c) * CS_STRIDE + slice] = ps;
    }
    __syncthreads();
    {
        unsigned short* dst = sfT + (size_t)b * N_ * C_;
#pragma unroll
        for (int st = 0; st < 2; ++st) {
            int g = st * 256 + tid;          // [0,512)
            int mr = g >> 4, p = g & 15;
            int sw = (mr & 15) ^ ((mr >> 1) & 4);   // sigma(m mod 16)
            int lch = p ^ sw;                       // baked XOR swizzle
            const unsigned short* src = &TA[mr][lch * 8];
            ushort4 a = *(const ushort4*)src;
            ushort4 bq = *(const ushort4*)(src + 4);
            uint4 w;
            w.x = a.x | ((unsigned)a.y << 16);   w.y = a.z | ((unsigned)a.w << 16);
            w.z = bq.x | ((unsigned)bq.y << 16); w.w = bq.z | ((unsigned)bq.w << 16);
            *(uint4*)&dst[(size_t)(m0 + mr) * C_ + p * 8] = w;
        }
    }
    __syncthreads();   // T reuse

    // ---- phase B: qfT V-panels [t][p][c][8] ----
    unsigned short (*TB)[34] = (unsigned short (*)[34])T;     // [128][34]
#pragma unroll
    for (int st = 0; st < 4; ++st) {
        int idx = st * 256 + tid;            // [0,1024)
        int r = idx >> 5, c4 = (idx & 31) * 4;
        float4 v = *(const float4*)&qb[(size_t)(m0 + r) * C_ + c4];
        TB[c4 + 0][r] = f2bf(v.x);
        TB[c4 + 1][r] = f2bf(v.y);
        TB[c4 + 2][r] = f2bf(v.z);
        TB[c4 + 3][r] = f2bf(v.w);
    }
    __syncthreads();
    {
        unsigned short* dstb = qfT + (size_t)b * N_ * C_;
        const int tile = m0 >> 6, pbase = (m0 & 32) >> 3;     // 0 or 4
#pragma unroll
        for (int st = 0; st < 2; ++st) {
            int g = st * 256 + tid;          // [0,512)
            int pl = g >> 7, c = g & 127;
            const unsigned short* src = &TB[c][pl * 8];
            ushort2 a0 = *(const ushort2*)(src);
            ushort2 a1 = *(const ushort2*)(src + 2);
            ushort2 a2 = *(const ushort2*)(src + 4);
            ushort2 a3 = *(const ushort2*)(src + 6);
            uint4 w;
            w.x = a0.x | ((unsigned)a0.y << 16); w.y = a1.x | ((unsigned)a1.y << 16);
            w.z = a2.x | ((unsigned)a2.y << 16); w.w = a3.x | ((unsigned)a3.y << 16);
            *(uint4*)&dstb[((size_t)tile * 8 + pbase + pl) * (C_ * 8) + c * 8] = w;
        }
    }
}

// ---------------------------------------------------------------------------
// Single-pass fused kernel (round-3 structure + counted-vmcnt pipeline).
// grid = 25 q-tiles x 8 batches = 200 blocks of 512 threads. 512-thread
// block => 2 waves/SIMD always => hard per-wave budget 256 regs: rt=2
// state (~180 incl. acc + vf preload) fits; rt=4 (rounds 5/6) spilled.
// Main loop: raw s_barrier + s_waitcnt vmcnt(4) -- prefetch loads stay in
// flight across barriers (T4); no vmcnt(0) drain except the last tile.
// P pack via v_cvt_pk_bf16_f32 (4 ops vs ~20); V fragments preloaded into
// registers before QK so their LDS latency hides under the QK MFMAs.
// ---------------------------------------------------------------------------
__global__ __launch_bounds__(512, 1) void fused_full_kernel(
    const float* __restrict__ q, const float* __restrict__ s,
    const float* __restrict__ csump,
    const unsigned short* __restrict__ sfT,
    const unsigned short* __restrict__ qfT,
    float* __restrict__ out0, float* __restrict__ out1) {

    // union: staging Kb[2][8192]+Vb[2][8192] shorts (64KB) | Of[128][132] f32
    __shared__ __align__(16) unsigned char SM[QTBIG * 132 * 4];   // 67584B
    __shared__ float dred[2][QTBIG];
    __shared__ float mskd[QTBIG];
    __shared__ float cs[C_];

    unsigned short* Kb = (unsigned short*)SM;             // [2][MT*C_]
    unsigned short* Vb = (unsigned short*)(SM + 32768);   // [2][MT*C_]
    float (*Of)[132] = (float (*)[132])SM;                // [128][132]

    const int tid = threadIdx.x;
    const int lane = tid & 63;
    const int wave = tid >> 6;             // 0..7
    const int l15 = lane & 15;
    const int quad = lane >> 4;
    const int qs = wave >> 1;              // q-subgroup: rows qs*32..qs*32+31
    const int mg = wave & 1;               // m-group: m-sub mg*32..mg*32+31
    const int bid = blockIdx.x;
    const int b = bid & 7;                 // XCD-pinned batch
    const int qt = bid >> 3;               // 0..24
    const int n0 = qt * QTBIG;

    const float* qb = q + (size_t)b * C_ * N_;
    const unsigned short* sfTb = sfT + (size_t)b * N_ * C_;
    const unsigned short* qfTb = qfT + (size_t)b * N_ * C_;

    // sigma(l15) base: permuted-m row so exp'd C-values form the PV A-frag
    const int sig_base = ((l15 >> 2) << 3) + (l15 & 3);

    // ---- prologue: async-stage tile 0 into buffer 0 ----
#pragma unroll
    for (int st = 0; st < 2; ++st) {
        int i = st * 512 + tid;
        gl_lds16(sfTb + (size_t)(i >> 4) * C_ + (i & 15) * 8,
                 &Kb[(st * 512 + wave * 64) * 8]);
        gl_lds16(qfTb + (size_t)i * 8,
                 &Vb[(st * 512 + wave * 64) * 8]);
    }

    // ---- csum gather: contiguous per-channel partial sums ----
    if (tid < C_) {
        float a = 0.f;
        const float* cp = csump + ((size_t)b * C_ + tid) * CS_STRIDE;
#pragma unroll 7
        for (int sl = 0; sl < SLICES; ++sl) a += cp[sl];
        cs[tid] = a;
    }
    __syncthreads();   // cs visible; prologue staging drained (once)

    // ---- Q fragments (registers for all tiles) + fp32 mask-dot ----
    bf16x8 qa[2][4];
    float dotp[2];
#pragma unroll
    for (int rt = 0; rt < 2; ++rt) {
        int grow = n0 + qs * 32 + rt * 16 + l15;
        if (grow > N_ - 1) grow = N_ - 1;   // pad rows duplicate last row
        float dp = 0.f;
#pragma unroll
        for (int ks = 0; ks < 4; ++ks) {
            int c0 = ks * 32 + quad * 8;
            float4 f0 = *(const float4*)&qb[(size_t)grow * C_ + c0];
            float4 f1 = *(const float4*)&qb[(size_t)grow * C_ + c0 + 4];
            dp += f0.x * cs[c0 + 0] + f0.y * cs[c0 + 1] +
                  f0.z * cs[c0 + 2] + f0.w * cs[c0 + 3] +
                  f1.x * cs[c0 + 4] + f1.y * cs[c0 + 5] +
                  f1.z * cs[c0 + 6] + f1.w * cs[c0 + 7];
            union { unsigned w[4]; bf16x8 v; } t;
            t.w[0] = cvtpk(f0.x, f0.y); t.w[1] = cvtpk(f0.z, f0.w);
            t.w[2] = cvtpk(f1.x, f1.y); t.w[3] = cvtpk(f1.z, f1.w);
            qa[rt][ks] = t.v;
        }
        dotp[rt] = dp;
    }
#pragma unroll
    for (int rt = 0; rt < 2; ++rt) {
        float d = dotp[rt];
        d += __shfl_xor(d, 16, 64);
        d += __shfl_xor(d, 32, 64);
        if (mg == 0 && quad == 0) mskd[qs * 32 + rt * 16 + l15] = d;
    }

    f32x4 O[2][8];
#pragma unroll
    for (int rt = 0; rt < 2; ++rt)
#pragma unroll
        for (int nt = 0; nt < 8; ++nt) O[rt][nt] = (f32x4){0.f, 0.f, 0.f, 0.f};
    float dsum[2] = {0.f, 0.f};

    for (int tt = 0; tt < TILES; ++tt) {
        const int cur = tt & 1;

        // barrier A: all waves done reading buf nxt (prev iteration's tile)
        __builtin_amdgcn_s_barrier();

        if (tt + 1 < TILES) {             // async-prefetch next tile
            const int nxt = cur ^ 1;
            const size_t m1 = (size_t)(tt + 1) * MT;
#pragma unroll
            for (int st = 0; st < 2; ++st) {
                int i = st * 512 + tid;
                gl_lds16(sfTb + (m1 + (i >> 4)) * C_ + (i & 15) * 8,
                         &Kb[nxt * (MT * C_) + (st * 512 + wave * 64) * 8]);
                gl_lds16(qfTb + (size_t)(tt + 1) * (MT * C_) + (size_t)i * 8,
                         &Vb[nxt * (MT * C_) + (st * 512 + wave * 64) * 8]);
            }
            // my 4 loads for cur (issued last iter) landed; 4 new stay in flight
            asm volatile("s_waitcnt vmcnt(4)" ::: "memory");
        } else {
            asm volatile("s_waitcnt vmcnt(0)" ::: "memory");
        }
        // barrier B: every wave's cur-tile staging landed -> visible block-wide
        __builtin_amdgcn_s_barrier();

        // ---- preload V fragments (independent of QK -> latency overlaps) ----
        bf16x8 vfr[8];
#pragma unroll
        for (int nt = 0; nt < 8; ++nt)
            vfr[nt] = *(const bf16x8*)&Vb[cur * (MT * C_) + ((mg * 4 + quad) * C_ + nt * 16 + l15) * 8];

        // ---- scoresT: rows = permuted m (wave's 32-m sub), cols = q-rows ----
        f32x4 acc[2][2];
        __builtin_amdgcn_s_setprio(1);
#pragma unroll
        for (int ct = 0; ct < 2; ++ct) {
            const int mrow = sig_base + (ct << 2);              // 0..31 perm
            const int sw = (mrow & 15) ^ ((mrow >> 1) & 4);     // sigma(m)
            const int row = mg * 32 + mrow;
            acc[ct][0] = (f32x4){0.f, 0.f, 0.f, 0.f};
            acc[ct][1] = (f32x4){0.f, 0.f, 0.f, 0.f};
#pragma unroll
            for (int ks = 0; ks < 4; ++ks) {
                int ch = (ks * 4 + quad) ^ sw;                  // un-swizzle
                bf16x8 af = *(const bf16x8*)&Kb[cur * (MT * C_) + row * C_ + ch * 8];
                acc[ct][0] = __builtin_amdgcn_mfma_f32_16x16x32_bf16(af, qa[0][ks], acc[ct][0], 0, 0, 0);
                acc[ct][1] = __builtin_amdgcn_mfma_f32_16x16x32_bf16(af, qa[1][ks], acc[ct][1], 0, 0, 0);
            }
        }
        __builtin_amdgcn_s_setprio(0);

        // ---- exp + cvt_pk pack into PV A-fragments ----
        bf16x8 pa[2];
#pragma unroll
        for (int rt = 0; rt < 2; ++rt) {
            float e0 = __expf(acc[0][rt][0]);
            float e1 = __expf(acc[0][rt][1]);
            float e2 = __expf(acc[0][rt][2]);
            float e3 = __expf(acc[0][rt][3]);
            float e4 = __expf(acc[1][rt][0]);
            float e5 = __expf(acc[1][rt][1]);
            float e6 = __expf(acc[1][rt][2]);
            float e7 = __expf(acc[1][rt][3]);
            dsum[rt] += ((e0 + e1) + (e2 + e3)) + ((e4 + e5) + (e6 + e7));
            union { unsigned w[4]; bf16x8 v; } pk;
            pk.w[0] = cvtpk(e0, e1); pk.w[1] = cvtpk(e2, e3);
            pk.w[2] = cvtpk(e4, e5); pk.w[3] = cvtpk(e6, e7);
            pa[rt] = pk.v;
        }

        // ---- PV: O[rt][nt] += P x V (V already in registers) ----
        __builtin_amdgcn_s_setprio(1);
#pragma unroll
        for (int nt = 0; nt < 8; ++nt) {
            O[0][nt] = __builtin_amdgcn_mfma_f32_16x16x32_bf16(pa[0], vfr[nt], O[0][nt], 0, 0, 0);
            O[1][nt] = __builtin_amdgcn_mfma_f32_16x16x32_bf16(pa[1], vfr[nt], O[1][nt], 0, 0, 0);
        }
        __builtin_amdgcn_s_setprio(0);
    }

    // ---- denominator: reduce over quads, publish per m-group ----
#pragma unroll
    for (int rt = 0; rt < 2; ++rt) {
        float d = dsum[rt];
        d += __shfl_xor(d, 16, 64);
        d += __shfl_xor(d, 32, 64);
        if (quad == 0) dred[mg][qs * 32 + rt * 16 + l15] = d;
    }

    __syncthreads();   // all PV reads of staging done; SM becomes Of

    // ---- O cross-m-group reduction via LDS (union buffer) ----
    if (mg == 1) {
#pragma unroll
        for (int rt = 0; rt < 2; ++rt)
#pragma unroll
            for (int nt = 0; nt < 8; ++nt)
#pragma unroll
                for (int r = 0; r < 4; ++r)
                    Of[qs * 32 + rt * 16 + quad * 4 + r][nt * 16 + l15] = O[rt][nt][r];
    }
    __syncthreads();
    if (mg == 0) {
#pragma unroll
        for (int rt = 0; rt < 2; ++rt)
#pragma unroll
            for (int nt = 0; nt < 8; ++nt)
#pragma unroll
                for (int r = 0; r < 4; ++r)
                    Of[qs * 32 + rt * 16 + quad * 4 + r][nt * 16 + l15] += O[rt][nt][r];
    }
    __syncthreads();

    // ---- final coalesced pass: normalize, mask, residuals, both outputs ----
    const size_t vbase = (size_t)b * N_ * C_ + (size_t)n0 * C_;
#pragma unroll
    for (int it = 0; it < 8; ++it) {
        int row = it * 16 + (tid >> 5);
        int grow = n0 + row;
        if (grow >= N_) continue;
        int c = (tid & 31) * 4;
        float dt = dred[0][row] + dred[1][row];
        float mk = 1.0f / (1.0f + __expf(-mskd[row]));
        float scl = mk / dt;
        float om = 1.0f + mk;
        float4 o4 = *(const float4*)&Of[row][c];
        float4 q4 = *(const float4*)&q[vbase + (size_t)row * C_ + c];
        float4 s4 = *(const float4*)&s[vbase + (size_t)row * C_ + c];
        float4 r0v, r1v;
        r0v.x = q4.x + o4.x * scl;
        r0v.y = q4.y + o4.y * scl;
        r0v.z = q4.z + o4.z * scl;
        r0v.w = q4.w + o4.w * scl;
        r1v.x = s4.x * om; r1v.y = s4.y * om;
        r1v.z = s4.z * om; r1v.w = s4.w * om;
        *(float4*)&out0[vbase + (size_t)row * C_ + c] = r0v;
        *(float4*)&out1[vbase + (size_t)row * C_ + c] = r1v;
    }
}

// ---------------------------------------------------------------------------
// fp32 fallback kernel (only if ws_size too small for sfT/qfT).
// ---------------------------------------------------------------------------
__global__ __launch_bounds__(256, 2) void fused_kernel(const float* __restrict__ q,
                                                       const float* __restrict__ s,
                                                       const float* __restrict__ csum,
                                                       float* __restrict__ out0,
                                                       float* __restrict__ out1) {
    __shared__ float QtT[C_][68];
    __shared__ float Kt[C_ * 32];
    __shared__ float Vt[32 * C_];
    __shared__ float PT[32][68];
    __shared__ float mask_l[64];
    __shared__ float csum_l[C_];

    const int t = threadIdx.x;
    const int l = t & 63, w = t >> 6, tx = t & 15, ty = t >> 4;
    const int bid = blockIdx.x, b = bid & 7, n0 = (bid >> 3) * 64;
    const float* qb = q + (size_t)b * C_ * N_;
    const float* sb = s + (size_t)b * C_ * N_;

#pragma unroll
    for (int jj = 0; jj < 2; ++jj) {
        int c = l + 64 * jj;
#pragma unroll
        for (int i = 0; i < 16; ++i) QtT[c][w + 4 * i] = qb[(size_t)(n0 + w + 4 * i) * C_ + c];
    }
    if (t < C_) csum_l[t] = csum[b * C_ + t];
    __syncthreads();
    if (t < 64) {
        float d = 0.f;
        for (int c = 0; c < C_; ++c) d += QtT[c][t] * csum_l[c];
        mask_l[t] = 1.0f / (1.0f + __expf(-d));
    }
    float4 Oa[4], Ob[4];
#pragma unroll
    for (int i = 0; i < 4; ++i) { Oa[i] = make_float4(0,0,0,0); Ob[i] = make_float4(0,0,0,0); }
    float m_r[4], l_r[4];
#pragma unroll
    for (int i = 0; i < 4; ++i) { m_r[i] = -3.0e38f; l_r[i] = 0.f; }

    for (int mt = 0; mt < N_ / 32; ++mt) {
        const int m0 = mt * 32;
        __syncthreads();
#pragma unroll
        for (int i = 0; i < 4; ++i) {
            int s4 = (w * 4 + i) * 64 + l;
            int c = s4 >> 3, mq = (s4 & 7) * 4;
            *(float4*)&Kt[c * 32 + mq] = *(const float4*)&sb[(size_t)c * N_ + m0 + mq];
            *(float4*)&Vt[s4 * 4] = *(const float4*)&qb[(size_t)m0 * C_ + s4 * 4];
        }
        __syncthreads();
        float a[4][2];
#pragma unroll
        for (int i = 0; i < 4; ++i) a[i][0] = a[i][1] = 0.f;
#pragma unroll 4
        for (int k = 0; k < C_; ++k) {
            const float4 qv = *(const float4*)&QtT[k][4 * ty];
            const float2 kv = *(const float2*)&Kt[k * 32 + 2 * tx];
            a[0][0] = fmaf(qv.x, kv.x, a[0][0]); a[0][1] = fmaf(qv.x, kv.y, a[0][1]);
            a[1][0] = fmaf(qv.y, kv.x, a[1][0]); a[1][1] = fmaf(qv.y, kv.y, a[1][1]);
            a[2][0] = fmaf(qv.z, kv.x, a[2][0]); a[2][1] = fmaf(qv.z, kv.y, a[2][1]);
            a[3][0] = fmaf(qv.w, kv.x, a[3][0]); a[3][1] = fmaf(qv.w, kv.y, a[3][1]);
        }
#pragma unroll
        for (int i = 0; i < 4; ++i) {
            float tm = fmaxf(a[i][0], a[i][1]);
            tm = fmaxf(tm, __shfl_xor(tm, 1, 64)); tm = fmaxf(tm, __shfl_xor(tm, 2, 64));
            tm = fmaxf(tm, __shfl_xor(tm, 4, 64)); tm = fmaxf(tm, __shfl_xor(tm, 8, 64));
            float nm = fmaxf(m_r[i], tm);
            float al = __expf(m_r[i] - nm);
            m_r[i] = nm;
            float p0 = __expf(a[i][0] - nm), p1 = __expf(a[i][1] - nm);
            float ts = p0 + p1;
            ts += __shfl_xor(ts, 1, 64); ts += __shfl_xor(ts, 2, 64);
            ts += __shfl_xor(ts, 4, 64); ts += __shfl_xor(ts, 8, 64);
            l_r[i] = l_r[i] * al + ts;
            PT[2 * tx + 0][4 * ty + i] = p0;
            PT[2 * tx + 1][4 * ty + i] = p1;
            Oa[i].x *= al; Oa[i].y *= al; Oa[i].z *= al; Oa[i].w *= al;
            Ob[i].x *= al; Ob[i].y *= al; Ob[i].z *= al; Ob[i].w *= al;
        }
        __syncthreads();
#pragma unroll 2
        for (int j = 0; j < 32; ++j) {
            const float4 pv = *(const float4*)&PT[j][4 * ty];
            const float4 v0 = *(const float4*)&Vt[j * C_ + 4 * tx];
            const float4 v1 = *(const float4*)&Vt[j * C_ + 4 * tx + 64];
            Oa[0].x = fmaf(pv.x, v0.x, Oa[0].x); Oa[0].y = fmaf(pv.x, v0.y, Oa[0].y);
            Oa[0].z = fmaf(pv.x, v0.z, Oa[0].z); Oa[0].w = fmaf(pv.x, v0.w, Oa[0].w);
            Ob[0].x = fmaf(pv.x, v1.x, Ob[0].x); Ob[0].y = fmaf(pv.x, v1.y, Ob[0].y);
            Ob[0].z = fmaf(pv.x, v1.z, Ob[0].z); Ob[0].w = fmaf(pv.x, v1.w, Ob[0].w);
            Oa[1].x = fmaf(pv.y, v0.x, Oa[1].x); Oa[1].y = fmaf(pv.y, v0.y, Oa[1].y);
            Oa[1].z = fmaf(pv.y, v0.z, Oa[1].z); Oa[1].w = fmaf(pv.y, v0.w, Oa[1].w);
            Ob[1].x = fmaf(pv.y, v1.x, Ob[1].x); Ob[1].y = fmaf(pv.y, v1.y, Ob[1].y);
            Ob[1].z = fmaf(pv.y, v1.z, Ob[1].z); Ob[1].w = fmaf(pv.y, v1.w, Ob[1].w);
            Oa[2].x = fmaf(pv.z, v0.x, Oa[2].x); Oa[2].y = fmaf(pv.z, v0.y, Oa[2].y);
            Oa[2].z = fmaf(pv.z, v0.z, Oa[2].z); Oa[2].w = fmaf(pv.z, v0.w, Oa[2].w);
            Ob[2].x = fmaf(pv.z, v1.x, Ob[2].x); Ob[2].y = fmaf(pv.z, v1.y, Ob[2].y);
            Ob[2].z = fmaf(pv.z, v1.z, Ob[2].z); Ob[2].w = fmaf(pv.z, v1.w, Ob[2].w);
            Oa[3].x = fmaf(pv.w, v0.x, Oa[3].x); Oa[3].y = fmaf(pv.w, v0.y, Oa[3].y);
            Oa[3].z = fmaf(pv.w, v0.z, Oa[3].z); Oa[3].w = fmaf(pv.w, v0.w, Oa[3].w);
            Ob[3].x = fmaf(pv.w, v1.x, Ob[3].x); Ob[3].y = fmaf(pv.w, v1.y, Ob[3].y);
            Ob[3].z = fmaf(pv.w, v1.z, Ob[3].z); Ob[3].w = fmaf(pv.w, v1.w, Ob[3].w);
        }
    }
#pragma unroll
    for (int i = 0; i < 4; ++i) {
        const int r = 4 * ty + i;
        const float mk = mask_l[r];
        const float scl = mk / l_r[i];
        const float om = 1.0f + mk;
        const size_t row = (size_t)b * C_ * N_ + (size_t)(n0 + r) * C_;
#pragma unroll
        for (int h = 0; h < 2; ++h) {
            const int c = 4 * tx + 64 * h;
            const float4 ov = h ? Ob[i] : Oa[i];
            float4 qv = *(const float4*)&qb[(size_t)(n0 + r) * C_ + c];
            float4 sv = *(const float4*)&sb[(size_t)(n0 + r) * C_ + c];
            float4 o0, o1;
            o0.x = qv.x + ov.x * scl; o0.y = qv.y + ov.y * scl;
            o0.z = qv.z + ov.z * scl; o0.w = qv.w + ov.w * scl;
            o1.x = sv.x * om; o1.y = sv.y * om; o1.z = sv.z * om; o1.w = sv.w * om;
            *(float4*)&out0[row + c] = o0;
            *(float4*)&out1[row + c] = o1;
        }
    }
}

extern "C" void kernel_launch(void* const* d_in, const int* in_sizes, int n_in,
                              void* d_out, int out_size, void* d_ws, size_t ws_size,
                              hipStream_t stream) {
    const float* q = (const float*)d_in[0];
    const float* s = (const float*)d_in[1];
    float* out0 = (float*)d_out;
    float* out1 = out0 + (size_t)B_ * C_ * N_;

    const size_t elems = (size_t)B_ * N_ * C_;              // 3.21M
    const size_t csump_sz = (size_t)B_ * C_ * CS_STRIDE;    // 102400 floats
    const size_t need = csump_sz * sizeof(float)
                      + 2 * elems * sizeof(unsigned short); // sfT + qfT

    if (ws_size >= need) {
        float* csump = (float*)d_ws;
        unsigned short* sfT = (unsigned short*)(csump + csump_sz);
        unsigned short* qfT = sfT + elems;
        prep_kernel<<<B_ * SLICES, 256, 0, stream>>>(q, s, sfT, qfT, csump);
        fused_full_kernel<<<QTILES * B_, 512, 0, stream>>>(q, s, csump, sfT, qfT, out0, out1);
    } else {
        float* csum = (float*)d_ws;                   // 4KB
        colsum_kernel<<<B_ * C_, 256, 0, stream>>>(s, csum);
        fused_kernel<<<B_ * (N_ / 64), 256, 0, stream>>>(q, s, csum, out0, out1);
    }
}

// Round 8
// 145.642 us; speedup vs baseline: 1.1928x; 1.0474x over previous
//
#include <hip/hip_runtime.h>
#include <math.h>

#define B_ 8
#define C_ 128
#define N_ 3136          // 56*56
#define MT 64            // m per tile
#define TILES 49         // N_/MT
#define SLICES 98        // prep: N_/32
#define QTB 64           // q rows per block (N_ = 49*64 exactly)
#define QTILES 49        // N_/QTB
#define CS_STRIDE 100    // csump padded slice stride

typedef short bf16x8 __attribute__((ext_vector_type(8)));
typedef float f32x4 __attribute__((ext_vector_type(4)));

__device__ __forceinline__ unsigned short f2bf(float f) {
    union { float f; unsigned u; } x; x.f = f;
    return (unsigned short)((x.u + 0x8000u) >> 16);   // round-half-up to bf16
}

__device__ __forceinline__ unsigned cvtpk(float lo, float hi) {
    unsigned r;
    asm("v_cvt_pk_bf16_f32 %0, %1, %2" : "=v"(r) : "v"(lo), "v"(hi));
    return r;
}

__device__ __forceinline__ void gl_lds16(const void* g, void* l) {
    __builtin_amdgcn_global_load_lds(
        (const __attribute__((address_space(1))) unsigned int*)g,
        (__attribute__((address_space(3))) unsigned int*)l, 16, 0, 0);
}

// ---------------------------------------------------------------------------
// colsum (fallback path only)
// ---------------------------------------------------------------------------
__global__ __launch_bounds__(256) void colsum_kernel(const float* __restrict__ s,
                                                     float* __restrict__ csum) {
    int blk = blockIdx.x;  // = b*C_ + c
    const float* p = s + (size_t)blk * N_;
    float acc = 0.f;
    for (int i = threadIdx.x; i < N_; i += 256) acc += p[i];
#pragma unroll
    for (int off = 32; off > 0; off >>= 1) acc += __shfl_down(acc, off, 64);
    __shared__ float part[4];
    if ((threadIdx.x & 63) == 0) part[threadIdx.x >> 6] = acc;
    __syncthreads();
    if (threadIdx.x == 0) csum[blk] = part[0] + part[1] + part[2] + part[3];
}

// ---------------------------------------------------------------------------
// Prepass, per (b, 32-m slice) -- 784 blocks (~3/CU) for latency hiding:
//   sfT[b][m][c] bf16, chunks XOR-swizzled by sigma(m)=(m&15)^((m>>1)&4)
//   qfT[b][tile64 t][p(8)][c][8] bf16 V-panels (PV fragment layout)
//   csump[b][c][slice] = partial column sums of s (deterministic)
// ---------------------------------------------------------------------------
__global__ __launch_bounds__(256) void prep_kernel(const float* __restrict__ q,
                                                   const float* __restrict__ s,
                                                   unsigned short* __restrict__ sfT,
                                                   unsigned short* __restrict__ qfT,
                                                   float* __restrict__ csump) {
    __shared__ unsigned short T[4608];   // 9.2KB, reused by both phases
    const int tid = threadIdx.x, bid = blockIdx.x;
    const int b = bid & 7, m0 = (bid >> 3) * 32;
    const int slice = bid >> 3;          // 0..97
    const float* sb = s + (size_t)b * C_ * N_;
    const float* qb = q + (size_t)b * C_ * N_;

    // ---- phase A: transpose s [c][32m] -> TA[32][c] + colsum partials ----
    unsigned short (*TA)[132] = (unsigned short (*)[132])T;   // [32][132]
#pragma unroll
    for (int st = 0; st < 4; ++st) {
        int idx = st * 256 + tid;            // [0,1024)
        int c = idx >> 3, m4 = (idx & 7) * 4;
        float4 v = *(const float4*)&sb[(size_t)c * N_ + m0 + m4];
        TA[m4 + 0][c] = f2bf(v.x);
        TA[m4 + 1][c] = f2bf(v.y);
        TA[m4 + 2][c] = f2bf(v.z);
        TA[m4 + 3][c] = f2bf(v.w);
        float ps = (v.x + v.y) + (v.z + v.w);
        ps += __shfl_xor(ps, 1, 8);
        ps += __shfl_xor(ps, 2, 8);
        ps += __shfl_xor(ps, 4, 8);
        if ((tid & 7) == 0) csump[((size_t)b * C_ + c) * CS_STRIDE + slice] = ps;
    }
    __syncthreads();
    {
        unsigned short* dst = sfT + (size_t)b * N_ * C_;
#pragma unroll
        for (int st = 0; st < 2; ++st) {
            int g = st * 256 + tid;          // [0,512)
            int mr = g >> 4, p = g & 15;
            int sw = (mr & 15) ^ ((mr >> 1) & 4);   // sigma(m mod 16)
            int lch = p ^ sw;                       // baked XOR swizzle
            const unsigned short* src = &TA[mr][lch * 8];
            ushort4 a = *(const ushort4*)src;
            ushort4 bq = *(const ushort4*)(src + 4);
            uint4 w;
            w.x = a.x | ((unsigned)a.y << 16);   w.y = a.z | ((unsigned)a.w << 16);
            w.z = bq.x | ((unsigned)bq.y << 16); w.w = bq.z | ((unsigned)bq.w << 16);
            *(uint4*)&dst[(size_t)(m0 + mr) * C_ + p * 8] = w;
        }
    }
    __syncthreads();   // T reuse

    // ---- phase B: qfT V-panels [t][p][c][8] ----
    unsigned short (*TB)[34] = (unsigned short (*)[34])T;     // [128][34]
#pragma unroll
    for (int st = 0; st < 4; ++st) {
        int idx = st * 256 + tid;            // [0,1024)
        int r = idx >> 5, c4 = (idx & 31) * 4;
        float4 v = *(const float4*)&qb[(size_t)(m0 + r) * C_ + c4];
        TB[c4 + 0][r] = f2bf(v.x);
        TB[c4 + 1][r] = f2bf(v.y);
        TB[c4 + 2][r] = f2bf(v.z);
        TB[c4 + 3][r] = f2bf(v.w);
    }
    __syncthreads();
    {
        unsigned short* dstb = qfT + (size_t)b * N_ * C_;
        const int tile = m0 >> 6, pbase = (m0 & 32) >> 3;     // 0 or 4
#pragma unroll
        for (int st = 0; st < 2; ++st) {
            int g = st * 256 + tid;          // [0,512)
            int pl = g >> 7, c = g & 127;
            const unsigned short* src = &TB[c][pl * 8];
            ushort2 a0 = *(const ushort2*)(src);
            ushort2 a1 = *(const ushort2*)(src + 2);
            ushort2 a2 = *(const ushort2*)(src + 4);
            ushort2 a3 = *(const ushort2*)(src + 6);
            uint4 w;
            w.x = a0.x | ((unsigned)a0.y << 16); w.y = a1.x | ((unsigned)a1.y << 16);
            w.z = a2.x | ((unsigned)a2.y << 16); w.w = a3.x | ((unsigned)a3.y << 16);
            *(uint4*)&dstb[((size_t)tile * 8 + pbase + pl) * (C_ * 8) + c * 8] = w;
        }
    }
}

// ---------------------------------------------------------------------------
// Single-pass fused kernel, q-split for block-level overlap. grid = 49
// q-tiles (64 rows each; N = 49*64 exactly) x 8 batches = 392 blocks of 256
// threads (4 waves = 2 qs x 2 mg, rt=2 -- same per-wave reuse/registers as
// round 7). LDS ~65.3KB/block -> TWO INDEPENDENT blocks co-resident per CU:
// their barriers are decoupled, so QK/exp/PV phases drift across blocks and
// the MFMA/VALU/LDS pipes overlap (round-0 evidence: 2-block 64us vs
// 1x512-thread barrier-locked 81us) -- without round-0's m-split combine.
// Counted vmcnt(8) keeps prefetch in flight across barriers.
// ---------------------------------------------------------------------------
__global__ __launch_bounds__(256, 2) void fused_full_kernel(
    const float* __restrict__ q, const float* __restrict__ s,
    const float* __restrict__ csump,
    const unsigned short* __restrict__ sfT,
    const unsigned short* __restrict__ qfT,
    float* __restrict__ out0, float* __restrict__ out1) {

    // union: staging Kb[2][8192]+Vb[2][8192] shorts (64KB) | Of[64][132] f32
    __shared__ __align__(16) unsigned char SM[65536];
    __shared__ float dred[2][QTB];
    __shared__ float mskd[QTB];
    __shared__ float cs[C_];

    unsigned short* Kb = (unsigned short*)SM;             // [2][MT*C_]
    unsigned short* Vb = (unsigned short*)(SM + 32768);   // [2][MT*C_]
    float (*Of)[132] = (float (*)[132])SM;                // [64][132]

    const int tid = threadIdx.x;
    const int lane = tid & 63;
    const int wave = tid >> 6;             // 0..3
    const int l15 = lane & 15;
    const int quad = lane >> 4;
    const int qs = wave >> 1;              // q-subgroup: rows qs*32..qs*32+31
    const int mg = wave & 1;               // m-group: m-sub mg*32..mg*32+31
    const int bid = blockIdx.x;
    const int b = bid & 7;                 // XCD-pinned batch
    const int qt = bid >> 3;               // 0..48
    const int n0 = qt * QTB;

    const float* qb = q + (size_t)b * C_ * N_;
    const unsigned short* sfTb = sfT + (size_t)b * N_ * C_;
    const unsigned short* qfTb = qfT + (size_t)b * N_ * C_;

    // sigma(l15) base: permuted-m row so exp'd C-values form the PV A-frag
    const int sig_base = ((l15 >> 2) << 3) + (l15 & 3);

    // ---- prologue: async-stage tile 0 into buffer 0 (8 loads/thread) ----
#pragma unroll
    for (int st = 0; st < 4; ++st) {
        int i = st * 256 + tid;
        gl_lds16(sfTb + (size_t)(i >> 4) * C_ + (i & 15) * 8,
                 &Kb[(st * 256 + wave * 64) * 8]);
        gl_lds16(qfTb + (size_t)i * 8,
                 &Vb[(st * 256 + wave * 64) * 8]);
    }

    // ---- csum gather: contiguous per-channel partial sums ----
    if (tid < C_) {
        float a = 0.f;
        const float* cp = csump + ((size_t)b * C_ + tid) * CS_STRIDE;
#pragma unroll 7
        for (int sl = 0; sl < SLICES; ++sl) a += cp[sl];
        cs[tid] = a;
    }
    __syncthreads();   // cs visible; prologue staging drained (once)

    // ---- Q fragments (registers for all tiles) + fp32 mask-dot ----
    bf16x8 qa[2][4];
    float dotp[2];
#pragma unroll
    for (int rt = 0; rt < 2; ++rt) {
        int grow = n0 + qs * 32 + rt * 16 + l15;       // always < N_
        float dp = 0.f;
#pragma unroll
        for (int ks = 0; ks < 4; ++ks) {
            int c0 = ks * 32 + quad * 8;
            float4 f0 = *(const float4*)&qb[(size_t)grow * C_ + c0];
            float4 f1 = *(const float4*)&qb[(size_t)grow * C_ + c0 + 4];
            dp += f0.x * cs[c0 + 0] + f0.y * cs[c0 + 1] +
                  f0.z * cs[c0 + 2] + f0.w * cs[c0 + 3] +
                  f1.x * cs[c0 + 4] + f1.y * cs[c0 + 5] +
                  f1.z * cs[c0 + 6] + f1.w * cs[c0 + 7];
            union { unsigned w[4]; bf16x8 v; } t;
            t.w[0] = cvtpk(f0.x, f0.y); t.w[1] = cvtpk(f0.z, f0.w);
            t.w[2] = cvtpk(f1.x, f1.y); t.w[3] = cvtpk(f1.z, f1.w);
            qa[rt][ks] = t.v;
        }
        dotp[rt] = dp;
    }
#pragma unroll
    for (int rt = 0; rt < 2; ++rt) {
        float d = dotp[rt];
        d += __shfl_xor(d, 16, 64);
        d += __shfl_xor(d, 32, 64);
        if (mg == 0 && quad == 0) mskd[qs * 32 + rt * 16 + l15] = d;
    }

    f32x4 O[2][8];
#pragma unroll
    for (int rt = 0; rt < 2; ++rt)
#pragma unroll
        for (int nt = 0; nt < 8; ++nt) O[rt][nt] = (f32x4){0.f, 0.f, 0.f, 0.f};
    float dsum[2] = {0.f, 0.f};

    for (int tt = 0; tt < TILES; ++tt) {
        const int cur = tt & 1;

        // barrier A: all waves done reading buf nxt (prev iteration's tile)
        __builtin_amdgcn_s_barrier();

        if (tt + 1 < TILES) {             // async-prefetch next tile
            const int nxt = cur ^ 1;
            const size_t m1 = (size_t)(tt + 1) * MT;
#pragma unroll
            for (int st = 0; st < 4; ++st) {
                int i = st * 256 + tid;
                gl_lds16(sfTb + (m1 + (i >> 4)) * C_ + (i & 15) * 8,
                         &Kb[nxt * (MT * C_) + (st * 256 + wave * 64) * 8]);
                gl_lds16(qfTb + (size_t)(tt + 1) * (MT * C_) + (size_t)i * 8,
                         &Vb[nxt * (MT * C_) + (st * 256 + wave * 64) * 8]);
            }
            // my 8 loads for cur (issued last iter) landed; 8 new in flight
            asm volatile("s_waitcnt vmcnt(8)" ::: "memory");
        } else {
            asm volatile("s_waitcnt vmcnt(0)" ::: "memory");
        }
        // barrier B: every wave's cur-tile staging landed -> visible block-wide
        __builtin_amdgcn_s_barrier();

        // ---- preload V fragments (independent of QK -> latency overlaps) ----
        bf16x8 vfr[8];
#pragma unroll
        for (int nt = 0; nt < 8; ++nt)
            vfr[nt] = *(const bf16x8*)&Vb[cur * (MT * C_) + ((mg * 4 + quad) * C_ + nt * 16 + l15) * 8];

        // ---- scoresT: rows = permuted m (wave's 32-m sub), cols = q-rows ----
        f32x4 acc[2][2];
        __builtin_amdgcn_s_setprio(1);
#pragma unroll
        for (int ct = 0; ct < 2; ++ct) {
            const int mrow = sig_base + (ct << 2);              // 0..31 perm
            const int sw = (mrow & 15) ^ ((mrow >> 1) & 4);     // sigma(m)
            const int row = mg * 32 + mrow;
            acc[ct][0] = (f32x4){0.f, 0.f, 0.f, 0.f};
            acc[ct][1] = (f32x4){0.f, 0.f, 0.f, 0.f};
#pragma unroll
            for (int ks = 0; ks < 4; ++ks) {
                int ch = (ks * 4 + quad) ^ sw;                  // un-swizzle
                bf16x8 af = *(const bf16x8*)&Kb[cur * (MT * C_) + row * C_ + ch * 8];
                acc[ct][0] = __builtin_amdgcn_mfma_f32_16x16x32_bf16(af, qa[0][ks], acc[ct][0], 0, 0, 0);
                acc[ct][1] = __builtin_amdgcn_mfma_f32_16x16x32_bf16(af, qa[1][ks], acc[ct][1], 0, 0, 0);
            }
        }
        __builtin_amdgcn_s_setprio(0);

        // ---- exp + cvt_pk pack into PV A-fragments ----
        bf16x8 pa[2];
#pragma unroll
        for (int rt = 0; rt < 2; ++rt) {
            float e0 = __expf(acc[0][rt][0]);
            float e1 = __expf(acc[0][rt][1]);
            float e2 = __expf(acc[0][rt][2]);
            float e3 = __expf(acc[0][rt][3]);
            float e4 = __expf(acc[1][rt][0]);
            float e5 = __expf(acc[1][rt][1]);
            float e6 = __expf(acc[1][rt][2]);
            float e7 = __expf(acc[1][rt][3]);
            dsum[rt] += ((e0 + e1) + (e2 + e3)) + ((e4 + e5) + (e6 + e7));
            union { unsigned w[4]; bf16x8 v; } pk;
            pk.w[0] = cvtpk(e0, e1); pk.w[1] = cvtpk(e2, e3);
            pk.w[2] = cvtpk(e4, e5); pk.w[3] = cvtpk(e6, e7);
            pa[rt] = pk.v;
        }

        // ---- PV: O[rt][nt] += P x V (V already in registers) ----
        __builtin_amdgcn_s_setprio(1);
#pragma unroll
        for (int nt = 0; nt < 8; ++nt) {
            O[0][nt] = __builtin_amdgcn_mfma_f32_16x16x32_bf16(pa[0], vfr[nt], O[0][nt], 0, 0, 0);
            O[1][nt] = __builtin_amdgcn_mfma_f32_16x16x32_bf16(pa[1], vfr[nt], O[1][nt], 0, 0, 0);
        }
        __builtin_amdgcn_s_setprio(0);
    }

    // ---- denominator: reduce over quads, publish per m-group ----
#pragma unroll
    for (int rt = 0; rt < 2; ++rt) {
        float d = dsum[rt];
        d += __shfl_xor(d, 16, 64);
        d += __shfl_xor(d, 32, 64);
        if (quad == 0) dred[mg][qs * 32 + rt * 16 + l15] = d;
    }

    __syncthreads();   // all PV reads of staging done; SM becomes Of

    // ---- O cross-m-group reduction via LDS (union buffer) ----
    if (mg == 1) {
#pragma unroll
        for (int rt = 0; rt < 2; ++rt)
#pragma unroll
            for (int nt = 0; nt < 8; ++nt)
#pragma unroll
                for (int r = 0; r < 4; ++r)
                    Of[qs * 32 + rt * 16 + quad * 4 + r][nt * 16 + l15] = O[rt][nt][r];
    }
    __syncthreads();
    if (mg == 0) {
#pragma unroll
        for (int rt = 0; rt < 2; ++rt)
#pragma unroll
            for (int nt = 0; nt < 8; ++nt)
#pragma unroll
                for (int r = 0; r < 4; ++r)
                    Of[qs * 32 + rt * 16 + quad * 4 + r][nt * 16 + l15] += O[rt][nt][r];
    }
    __syncthreads();

    // ---- final coalesced pass: normalize, mask, residuals, both outputs ----
    const size_t vbase = (size_t)b * N_ * C_ + (size_t)n0 * C_;
#pragma unroll
    for (int it = 0; it < 8; ++it) {
        int row = it * 8 + (tid >> 5);               // 0..63, always valid
        int c = (tid & 31) * 4;
        float dt = dred[0][row] + dred[1][row];
        float mk = 1.0f / (1.0f + __expf(-mskd[row]));
        float scl = mk / dt;
        float om = 1.0f + mk;
        float4 o4 = *(const float4*)&Of[row][c];
        float4 q4 = *(const float4*)&q[vbase + (size_t)row * C_ + c];
        float4 s4 = *(const float4*)&s[vbase + (size_t)row * C_ + c];
        float4 r0v, r1v;
        r0v.x = q4.x + o4.x * scl;
        r0v.y = q4.y + o4.y * scl;
        r0v.z = q4.z + o4.z * scl;
        r0v.w = q4.w + o4.w * scl;
        r1v.x = s4.x * om; r1v.y = s4.y * om;
        r1v.z = s4.z * om; r1v.w = s4.w * om;
        *(float4*)&out0[vbase + (size_t)row * C_ + c] = r0v;
        *(float4*)&out1[vbase + (size_t)row * C_ + c] = r1v;
    }
}

// ---------------------------------------------------------------------------
// fp32 fallback kernel (only if ws_size too small for sfT/qfT).
// ---------------------------------------------------------------------------
__global__ __launch_bounds__(256, 2) void fused_kernel(const float* __restrict__ q,
                                                       const float* __restrict__ s,
                                                       const float* __restrict__ csum,
                                                       float* __restrict__ out0,
                                                       float* __restrict__ out1) {
    __shared__ float QtT[C_][68];
    __shared__ float Kt[C_ * 32];
    __shared__ float Vt[32 * C_];
    __shared__ float PT[32][68];
    __shared__ float mask_l[64];
    __shared__ float csum_l[C_];

    const int t = threadIdx.x;
    const int l = t & 63, w = t >> 6, tx = t & 15, ty = t >> 4;
    const int bid = blockIdx.x, b = bid & 7, n0 = (bid >> 3) * 64;
    const float* qb = q + (size_t)b * C_ * N_;
    const float* sb = s + (size_t)b * C_ * N_;

#pragma unroll
    for (int jj = 0; jj < 2; ++jj) {
        int c = l + 64 * jj;
#pragma unroll
        for (int i = 0; i < 16; ++i) QtT[c][w + 4 * i] = qb[(size_t)(n0 + w + 4 * i) * C_ + c];
    }
    if (t < C_) csum_l[t] = csum[b * C_ + t];
    __syncthreads();
    if (t < 64) {
        float d = 0.f;
        for (int c = 0; c < C_; ++c) d += QtT[c][t] * csum_l[c];
        mask_l[t] = 1.0f / (1.0f + __expf(-d));
    }
    float4 Oa[4], Ob[4];
#pragma unroll
    for (int i = 0; i < 4; ++i) { Oa[i] = make_float4(0,0,0,0); Ob[i] = make_float4(0,0,0,0); }
    float m_r[4], l_r[4];
#pragma unroll
    for (int i = 0; i < 4; ++i) { m_r[i] = -3.0e38f; l_r[i] = 0.f; }

    for (int mt = 0; mt < N_ / 32; ++mt) {
        const int m0 = mt * 32;
        __syncthreads();
#pragma unroll
        for (int i = 0; i < 4; ++i) {
            int s4 = (w * 4 + i) * 64 + l;
            int c = s4 >> 3, mq = (s4 & 7) * 4;
            *(float4*)&Kt[c * 32 + mq] = *(const float4*)&sb[(size_t)c * N_ + m0 + mq];
            *(float4*)&Vt[s4 * 4] = *(const float4*)&qb[(size_t)m0 * C_ + s4 * 4];
        }
        __syncthreads();
        float a[4][2];
#pragma unroll
        for (int i = 0; i < 4; ++i) a[i][0] = a[i][1] = 0.f;
#pragma unroll 4
        for (int k = 0; k < C_; ++k) {
            const float4 qv = *(const float4*)&QtT[k][4 * ty];
            const float2 kv = *(const float2*)&Kt[k * 32 + 2 * tx];
            a[0][0] = fmaf(qv.x, kv.x, a[0][0]); a[0][1] = fmaf(qv.x, kv.y, a[0][1]);
            a[1][0] = fmaf(qv.y, kv.x, a[1][0]); a[1][1] = fmaf(qv.y, kv.y, a[1][1]);
            a[2][0] = fmaf(qv.z, kv.x, a[2][0]); a[2][1] = fmaf(qv.z, kv.y, a[2][1]);
            a[3][0] = fmaf(qv.w, kv.x, a[3][0]); a[3][1] = fmaf(qv.w, kv.y, a[3][1]);
        }
#pragma unroll
        for (int i = 0; i < 4; ++i) {
            float tm = fmaxf(a[i][0], a[i][1]);
            tm = fmaxf(tm, __shfl_xor(tm, 1, 64)); tm = fmaxf(tm, __shfl_xor(tm, 2, 64));
            tm = fmaxf(tm, __shfl_xor(tm, 4, 64)); tm = fmaxf(tm, __shfl_xor(tm, 8, 64));
            float nm = fmaxf(m_r[i], tm);
            float al = __expf(m_r[i] - nm);
            m_r[i] = nm;
            float p0 = __expf(a[i][0] - nm), p1 = __expf(a[i][1] - nm);
            float ts = p0 + p1;
            ts += __shfl_xor(ts, 1, 64); ts += __shfl_xor(ts, 2, 64);
            ts += __shfl_xor(ts, 4, 64); ts += __shfl_xor(ts, 8, 64);
            l_r[i] = l_r[i] * al + ts;
            PT[2 * tx + 0][4 * ty + i] = p0;
            PT[2 * tx + 1][4 * ty + i] = p1;
            Oa[i].x *= al; Oa[i].y *= al; Oa[i].z *= al; Oa[i].w *= al;
            Ob[i].x *= al; Ob[i].y *= al; Ob[i].z *= al; Ob[i].w *= al;
        }
        __syncthreads();
#pragma unroll 2
        for (int j = 0; j < 32; ++j) {
            const float4 pv = *(const float4*)&PT[j][4 * ty];
            const float4 v0 = *(const float4*)&Vt[j * C_ + 4 * tx];
            const float4 v1 = *(const float4*)&Vt[j * C_ + 4 * tx + 64];
            Oa[0].x = fmaf(pv.x, v0.x, Oa[0].x); Oa[0].y = fmaf(pv.x, v0.y, Oa[0].y);
            Oa[0].z = fmaf(pv.x, v0.z, Oa[0].z); Oa[0].w = fmaf(pv.x, v0.w, Oa[0].w);
            Ob[0].x = fmaf(pv.x, v1.x, Ob[0].x); Ob[0].y = fmaf(pv.x, v1.y, Ob[0].y);
            Ob[0].z = fmaf(pv.x, v1.z, Ob[0].z); Ob[0].w = fmaf(pv.x, v1.w, Ob[0].w);
            Oa[1].x = fmaf(pv.y, v0.x, Oa[1].x); Oa[1].y = fmaf(pv.y, v0.y, Oa[1].y);
            Oa[1].z = fmaf(pv.y, v0.z, Oa[1].z); Oa[1].w = fmaf(pv.y, v0.w, Oa[1].w);
            Ob[1].x = fmaf(pv.y, v1.x, Ob[1].x); Ob[1].y = fmaf(pv.y, v1.y, Ob[1].y);
            Ob[1].z = fmaf(pv.y, v1.z, Ob[1].z); Ob[1].w = fmaf(pv.y, v1.w, Ob[1].w);
            Oa[2].x = fmaf(pv.z, v0.x, Oa[2].x); Oa[2].y = fmaf(pv.z, v0.y, Oa[2].y);
            Oa[2].z = fmaf(pv.z, v0.z, Oa[2].z); Oa[2].w = fmaf(pv.z, v0.w, Oa[2].w);
            Ob[2].x = fmaf(pv.z, v1.x, Ob[2].x); Ob[2].y = fmaf(pv.z, v1.y, Ob[2].y);
            Ob[2].z = fmaf(pv.z, v1.z, Ob[2].z); Ob[2].w = fmaf(pv.z, v1.w, Ob[2].w);
            Oa[3].x = fmaf(pv.w, v0.x, Oa[3].x); Oa[3].y = fmaf(pv.w, v0.y, Oa[3].y);
            Oa[3].z = fmaf(pv.w, v0.z, Oa[3].z); Oa[3].w = fmaf(pv.w, v0.w, Oa[3].w);
            Ob[3].x = fmaf(pv.w, v1.x, Ob[3].x); Ob[3].y = fmaf(pv.w, v1.y, Ob[3].y);
            Ob[3].z = fmaf(pv.w, v1.z, Ob[3].z); Ob[3].w = fmaf(pv.w, v1.w, Ob[3].w);
        }
    }
#pragma unroll
    for (int i = 0; i < 4; ++i) {
        const int r = 4 * ty + i;
        const float mk = mask_l[r];
        const float scl = mk / l_r[i];
        const float om = 1.0f + mk;
        const size_t row = (size_t)b * C_ * N_ + (size_t)(n0 + r) * C_;
#pragma unroll
        for (int h = 0; h < 2; ++h) {
            const int c = 4 * tx + 64 * h;
            const float4 ov = h ? Ob[i] : Oa[i];
            float4 qv = *(const float4*)&qb[(size_t)(n0 + r) * C_ + c];
            float4 sv = *(const float4*)&sb[(size_t)(n0 + r) * C_ + c];
            float4 o0, o1;
            o0.x = qv.x + ov.x * scl; o0.y = qv.y + ov.y * scl;
            o0.z = qv.z + ov.z * scl; o0.w = qv.w + ov.w * scl;
            o1.x = sv.x * om; o1.y = sv.y * om; o1.z = sv.z * om; o1.w = sv.w * om;
            *(float4*)&out0[row + c] = o0;
            *(float4*)&out1[row + c] = o1;
        }
    }
}

extern "C" void kernel_launch(void* const* d_in, const int* in_sizes, int n_in,
                              void* d_out, int out_size, void* d_ws, size_t ws_size,
                              hipStream_t stream) {
    const float* q = (const float*)d_in[0];
    const float* s = (const float*)d_in[1];
    float* out0 = (float*)d_out;
    float* out1 = out0 + (size_t)B_ * C_ * N_;

    const size_t elems = (size_t)B_ * N_ * C_;              // 3.21M
    const size_t csump_sz = (size_t)B_ * C_ * CS_STRIDE;    // 102400 floats
    const size_t need = csump_sz * sizeof(float)
                      + 2 * elems * sizeof(unsigned short); // sfT + qfT

    if (ws_size >= need) {
        float* csump = (float*)d_ws;
        unsigned short* sfT = (unsigned short*)(csump + csump_sz);
        unsigned short* qfT = sfT + elems;
        prep_kernel<<<B_ * SLICES, 256, 0, stream>>>(q, s, sfT, qfT, csump);
        fused_full_kernel<<<QTILES * B_, 256, 0, stream>>>(q, s, csump, sfT, qfT, out0, out1);
    } else {
        float* csum = (float*)d_ws;                   // 4KB
        colsum_kernel<<<B_ * C_, 256, 0, stream>>>(s, csum);
        fused_kernel<<<B_ * (N_ / 64), 256, 0, stream>>>(q, s, csum, out0, out1);
    }
}